// Round 5
// baseline (256.030 us; speedup 1.0000x reference)
//
#include <hip/hip_runtime.h>

#define BB 128
#define FF 512

typedef float v4f __attribute__((ext_vector_type(4)));

// Round-5 DIAGNOSTIC SPLIT. The fused kernel idles every pipe (VALU 9%,
// HBM 30%, LDS 0, occ 50%) yet takes ~80-85us on 270MB logical traffic.
// Split the per-row read->reduce->write coupling into two pure streams:
//   A: read-only hebb pass (regular loads: seed L2/L3) -> out (tiny write)
//   B: elementwise update pass (hebb re-read harvests L3; NT stores
//      no-allocate so they don't evict hebb lines B still needs)
// Counters per kernel discriminate: mixed-stream ceiling vs reduce-throttle.

// ---------- Kernel A: pre[b,j] -> out[b,j] = tanh(pre + input) ----------
__global__ __launch_bounds__(256) void pre_kernel(
    const float* __restrict__ input,
    const float* __restrict__ last_out,
    const float* __restrict__ hebb,
    const float* __restrict__ weight,
    const float* __restrict__ ps,
    float* __restrict__ out)            // B*F
{
    const int wave = threadIdx.x >> 6;
    const int lane = threadIdx.x & 63;
    const int row  = blockIdx.x * 4 + wave;     // 0 .. B*F-1
    const int b    = row >> 9;
    const int j    = row & (FF - 1);

    const size_t hbase  = (size_t)row * FF;
    const int    wbase  = j * FF;
    const int    lobase = b * FF;
    const int k0 = lane * 4;
    const int k1 = 256 + lane * 4;

    // Regular (caching) loads ON PURPOSE: leave hebb resident in L2/L3
    // so kernel B's re-read is a cache harvest, not a second HBM pass.
    const v4f h0 = *(const v4f*)(hebb     + hbase  + k0);
    const v4f h1 = *(const v4f*)(hebb     + hbase  + k1);
    const v4f w0 = *(const v4f*)(weight   + wbase  + k0);
    const v4f w1 = *(const v4f*)(weight   + wbase  + k1);
    const v4f p0 = *(const v4f*)(ps       + wbase  + k0);
    const v4f p1 = *(const v4f*)(ps       + wbase  + k1);
    const v4f l0 = *(const v4f*)(last_out + lobase + k0);
    const v4f l1 = *(const v4f*)(last_out + lobase + k1);

    float acc;
    acc = l0.x * fmaf(p0.x, h0.x, w0.x);
    acc = fmaf(l0.y, fmaf(p0.y, h0.y, w0.y), acc);
    acc = fmaf(l0.z, fmaf(p0.z, h0.z, w0.z), acc);
    acc = fmaf(l0.w, fmaf(p0.w, h0.w, w0.w), acc);
    acc = fmaf(l1.x, fmaf(p1.x, h1.x, w1.x), acc);
    acc = fmaf(l1.y, fmaf(p1.y, h1.y, w1.y), acc);
    acc = fmaf(l1.z, fmaf(p1.z, h1.z, w1.z), acc);
    acc = fmaf(l1.w, fmaf(p1.w, h1.w, w1.w), acc);

    #pragma unroll
    for (int off = 32; off > 0; off >>= 1)
        acc += __shfl_xor(acc, off, 64);

    if (lane == 0)
        out[lobase + j] = tanhf(acc + input[lobase + j]);
}

// ---------- Kernel B: hebb_new = fma(lr*o, lo - o*h, h) ----------
// Pure 1R:1W elementwise stream (the m13-copy analog + fma). No reduce,
// no shfl, no tanh — if THIS doesn't run at ~6 TB/s, the platform's
// mixed-stream ceiling is the answer and the fused kernel was roofline.
__global__ __launch_bounds__(256) void upd_kernel(
    const float* __restrict__ last_out,
    const float* __restrict__ hebb,
    const float* __restrict__ out,      // B*F (read, from pre_kernel)
    const float* __restrict__ lr_p,
    float* __restrict__ hebb_new)       // B*F*F
{
    const int wave = threadIdx.x >> 6;
    const int lane = threadIdx.x & 63;
    const int row  = blockIdx.x * 4 + wave;
    const int b    = row >> 9;
    const int j    = row & (FF - 1);

    const size_t hbase  = (size_t)row * FF;
    const int    lobase = b * FF;
    const int k0 = lane * 4;
    const int k1 = 256 + lane * 4;

    const float o = out[lobase + j];            // uniform per wave, L2-hit
    const float c = lr_p[0] * o;

    // Regular loads: harvest the L2/L3 residency kernel A just created.
    const v4f h0 = *(const v4f*)(hebb     + hbase  + k0);
    const v4f h1 = *(const v4f*)(hebb     + hbase  + k1);
    const v4f l0 = *(const v4f*)(last_out + lobase + k0);
    const v4f l1 = *(const v4f*)(last_out + lobase + k1);

    v4f n0, n1;
    n0.x = fmaf(c, l0.x - o * h0.x, h0.x);
    n0.y = fmaf(c, l0.y - o * h0.y, h0.y);
    n0.z = fmaf(c, l0.z - o * h0.z, h0.z);
    n0.w = fmaf(c, l0.w - o * h0.w, h0.w);
    n1.x = fmaf(c, l1.x - o * h1.x, h1.x);
    n1.y = fmaf(c, l1.y - o * h1.y, h1.y);
    n1.z = fmaf(c, l1.z - o * h1.z, h1.z);
    n1.w = fmaf(c, l1.w - o * h1.w, h1.w);

    // NT stores: no-allocate, don't evict the hebb lines B still needs.
    __builtin_nontemporal_store(n0, (v4f*)(hebb_new + hbase + k0));
    __builtin_nontemporal_store(n1, (v4f*)(hebb_new + hbase + k1));
}

extern "C" void kernel_launch(void* const* d_in, const int* in_sizes, int n_in,
                              void* d_out, int out_size, void* d_ws, size_t ws_size,
                              hipStream_t stream) {
    const float* input    = (const float*)d_in[0];
    const float* last_out = (const float*)d_in[1];
    const float* hebb     = (const float*)d_in[2];
    const float* weight   = (const float*)d_in[3];
    const float* ps       = (const float*)d_in[4];
    const float* lr       = (const float*)d_in[5];

    float* out      = (float*)d_out;            // first B*F floats
    float* hebb_new = out + BB * FF;            // then B*F*F floats

    const int blocks = (BB * FF) / 4;           // 16384 blocks, 4 waves each

    pre_kernel<<<blocks, 256, 0, stream>>>(input, last_out, hebb, weight, ps, out);
    upd_kernel<<<blocks, 256, 0, stream>>>(last_out, hebb, out, lr, hebb_new);
}

// Round 6
// 235.345 us; speedup vs baseline: 1.0879x; 1.0879x over previous
//
#include <hip/hip_runtime.h>

#define BB 128
#define FF 512

typedef float v4f __attribute__((ext_vector_type(4)));

// Round-6: best-known config (fused, NT hebb load/store) + 2 rows per wave.
// Rows r and r+32768 share j (32768 = 64*512): weight/ps loaded once per
// wave for both rows. All 12 vector loads issue before either reduce; the
// two 8-FMA chains and two 6-step butterflies interleave (2x ILP), and the
// wave holds 4 KB of hebb reads in flight instead of 2 KB. This is the last
// untested lever: per-wave outstanding-read bytes (all prior variants held
// <=2KB and all landed at ~5 B/cyc/CU, half the copy rate, with every PMC
// pipe idle and the NT>cached inversion ruling out HBM-BW-bound).
__global__ __launch_bounds__(256) void PlasticLinearRec_kernel(
    const float* __restrict__ input,
    const float* __restrict__ last_out,
    const float* __restrict__ hebb,
    const float* __restrict__ weight,
    const float* __restrict__ ps,
    const float* __restrict__ lr_p,
    float* __restrict__ out,       // B*F
    float* __restrict__ hebb_new)  // B*F*F
{
    const int wave = threadIdx.x >> 6;
    const int lane = threadIdx.x & 63;
    const int wid  = blockIdx.x * 4 + wave;     // 0 .. 32767
    const int j    = wid & (FF - 1);
    const int ba   = wid >> 9;                  // 0..63
    const int bb   = ba + 64;                   // 64..127

    const int k0 = lane * 4;
    const int k1 = 256 + lane * 4;

    const size_t ha = (size_t)wid * FF;             // hebb row (ba, j)
    const size_t hb = ha + (size_t)32768 * FF;      // hebb row (bb, j)
    const int    wb = j * FF;
    const int    la = ba * FF;
    const int    lb = bb * FF;

    // ---- issue ALL loads up front (12 vector + 2 scalar) ----
    const v4f h0a = __builtin_nontemporal_load((const v4f*)(hebb + ha + k0));
    const v4f h1a = __builtin_nontemporal_load((const v4f*)(hebb + ha + k1));
    const v4f h0b = __builtin_nontemporal_load((const v4f*)(hebb + hb + k0));
    const v4f h1b = __builtin_nontemporal_load((const v4f*)(hebb + hb + k1));
    const v4f w0  = *(const v4f*)(weight   + wb + k0);
    const v4f w1  = *(const v4f*)(weight   + wb + k1);
    const v4f p0  = *(const v4f*)(ps       + wb + k0);
    const v4f p1  = *(const v4f*)(ps       + wb + k1);
    const v4f l0a = *(const v4f*)(last_out + la + k0);
    const v4f l1a = *(const v4f*)(last_out + la + k1);
    const v4f l0b = *(const v4f*)(last_out + lb + k0);
    const v4f l1b = *(const v4f*)(last_out + lb + k1);
    const float ia = input[la + j];
    const float ib = input[lb + j];
    const float lr = lr_p[0];

    // ---- two independent FMA chains (interleaved by the scheduler) ----
    float aa, ab;
    aa = l0a.x * fmaf(p0.x, h0a.x, w0.x);
    ab = l0b.x * fmaf(p0.x, h0b.x, w0.x);
    aa = fmaf(l0a.y, fmaf(p0.y, h0a.y, w0.y), aa);
    ab = fmaf(l0b.y, fmaf(p0.y, h0b.y, w0.y), ab);
    aa = fmaf(l0a.z, fmaf(p0.z, h0a.z, w0.z), aa);
    ab = fmaf(l0b.z, fmaf(p0.z, h0b.z, w0.z), ab);
    aa = fmaf(l0a.w, fmaf(p0.w, h0a.w, w0.w), aa);
    ab = fmaf(l0b.w, fmaf(p0.w, h0b.w, w0.w), ab);
    aa = fmaf(l1a.x, fmaf(p1.x, h1a.x, w1.x), aa);
    ab = fmaf(l1b.x, fmaf(p1.x, h1b.x, w1.x), ab);
    aa = fmaf(l1a.y, fmaf(p1.y, h1a.y, w1.y), aa);
    ab = fmaf(l1b.y, fmaf(p1.y, h1b.y, w1.y), ab);
    aa = fmaf(l1a.z, fmaf(p1.z, h1a.z, w1.z), aa);
    ab = fmaf(l1b.z, fmaf(p1.z, h1b.z, w1.z), ab);
    aa = fmaf(l1a.w, fmaf(p1.w, h1a.w, w1.w), aa);
    ab = fmaf(l1b.w, fmaf(p1.w, h1b.w, w1.w), ab);

    // ---- two interleaved 64-lane butterflies ----
    #pragma unroll
    for (int off = 32; off > 0; off >>= 1) {
        aa += __shfl_xor(aa, off, 64);
        ab += __shfl_xor(ab, off, 64);
    }

    const float oa = tanhf(aa + ia);
    const float ob = tanhf(ab + ib);
    const float ca = lr * oa;
    const float cb = lr * ob;

    if (lane == 0) {
        out[la + j] = oa;
        out[lb + j] = ob;
    }

    v4f n0, n1;
    n0.x = fmaf(ca, l0a.x - oa * h0a.x, h0a.x);
    n0.y = fmaf(ca, l0a.y - oa * h0a.y, h0a.y);
    n0.z = fmaf(ca, l0a.z - oa * h0a.z, h0a.z);
    n0.w = fmaf(ca, l0a.w - oa * h0a.w, h0a.w);
    n1.x = fmaf(ca, l1a.x - oa * h1a.x, h1a.x);
    n1.y = fmaf(ca, l1a.y - oa * h1a.y, h1a.y);
    n1.z = fmaf(ca, l1a.z - oa * h1a.z, h1a.z);
    n1.w = fmaf(ca, l1a.w - oa * h1a.w, h1a.w);
    __builtin_nontemporal_store(n0, (v4f*)(hebb_new + ha + k0));
    __builtin_nontemporal_store(n1, (v4f*)(hebb_new + ha + k1));

    n0.x = fmaf(cb, l0b.x - ob * h0b.x, h0b.x);
    n0.y = fmaf(cb, l0b.y - ob * h0b.y, h0b.y);
    n0.z = fmaf(cb, l0b.z - ob * h0b.z, h0b.z);
    n0.w = fmaf(cb, l0b.w - ob * h0b.w, h0b.w);
    n1.x = fmaf(cb, l1b.x - ob * h1b.x, h1b.x);
    n1.y = fmaf(cb, l1b.y - ob * h1b.y, h1b.y);
    n1.z = fmaf(cb, l1b.z - ob * h1b.z, h1b.z);
    n1.w = fmaf(cb, l1b.w - ob * h1b.w, h1b.w);
    __builtin_nontemporal_store(n0, (v4f*)(hebb_new + hb + k0));
    __builtin_nontemporal_store(n1, (v4f*)(hebb_new + hb + k1));
}

extern "C" void kernel_launch(void* const* d_in, const int* in_sizes, int n_in,
                              void* d_out, int out_size, void* d_ws, size_t ws_size,
                              hipStream_t stream) {
    const float* input    = (const float*)d_in[0];
    const float* last_out = (const float*)d_in[1];
    const float* hebb     = (const float*)d_in[2];
    const float* weight   = (const float*)d_in[3];
    const float* ps       = (const float*)d_in[4];
    const float* lr       = (const float*)d_in[5];

    float* out      = (float*)d_out;            // first B*F floats
    float* hebb_new = out + BB * FF;            // then B*F*F floats

    const int blocks = 32768 / 4;               // 8192 blocks, 4 waves, 2 rows/wave

    PlasticLinearRec_kernel<<<blocks, 256, 0, stream>>>(
        input, last_out, hebb, weight, ps, lr, out, hebb_new);
}